// Round 2
// baseline (442.962 us; speedup 1.0000x reference)
//
#include <hip/hip_runtime.h>
#include <math.h>

#define VB 28
#define LL 64
#define PAD_TOK 26
#define EOS_TOK 27
#define NSLOT 34   // 0 loss,1 mask,2 consec,3 mexp,4 kl,5 cls,6..33 vocab
#define REPL 8     // replicated atomic banks, stride 64 floats
#define CNT_IDX 512

__device__ __forceinline__ float wave_red(float v) {
  #pragma unroll
  for (int o = 32; o > 0; o >>= 1) v += __shfl_down(v, o, 64);
  return v;
}

__global__ __launch_bounds__(256) void vae_fused(
    const float* __restrict__ x, const float* __restrict__ rec,
    const float* __restrict__ zm, const float* __restrict__ zlv,
    const float* __restrict__ cs, float* __restrict__ ws,
    float* __restrict__ out, int nrows, int nz, int nc, int nblocks) {
  __shared__ float w_pow[72];
  __shared__ float red[4][NSLOT];
  __shared__ float fin[NSLOT];
  __shared__ int last_flag;
  const int lane = threadIdx.x & 63;
  const int wid  = threadIdx.x >> 6;
  if (threadIdx.x < 72)
    w_pow[threadIdx.x] = (threadIdx.x < 62)
        ? __powf((float)(threadIdx.x + 1), 2.5f) : 0.f;
  __syncthreads();

  float loss_acc = 0.f, mask_cnt = 0.f, consec_acc = 0.f, mexp_cnt = 0.f;
  float vocab[VB];
  #pragma unroll
  for (int v = 0; v < VB; ++v) vocab[v] = 0.f;

  const int wave_id = blockIdx.x * 4 + wid;
  const int n_waves = nblocks * 4;

  for (int row = wave_id; row < nrows; row += n_waves) {
    const size_t base = ((size_t)row * LL + lane) * VB;
    const float4* xp = reinterpret_cast<const float4*>(x + base);
    const float4* rp = reinterpret_cast<const float4*>(rec + base);
    float r[VB];
    float best = -INFINITY, pt = 0.f;
    int tgt = 0;
    #pragma unroll
    for (int i = 0; i < 7; ++i) {
      float4 xq = xp[i];
      float4 rq = rp[i];
      r[i*4+0] = rq.x; r[i*4+1] = rq.y; r[i*4+2] = rq.z; r[i*4+3] = rq.w;
      if (xq.x > best) { best = xq.x; tgt = i*4+0; pt = rq.x; }
      if (xq.y > best) { best = xq.y; tgt = i*4+1; pt = rq.y; }
      if (xq.z > best) { best = xq.z; tgt = i*4+2; pt = rq.z; }
      if (xq.w > best) { best = xq.w; tgt = i*4+3; pt = rq.w; }
    }
    const float mask = (tgt != PAD_TOK) ? 1.f : 0.f;
    const float mexp = (tgt != PAD_TOK && tgt != EOS_TOK) ? 1.f : 0.f;
    loss_acc += -__logf(fminf(fmaxf(pt, 1e-7f), 1.f)) * mask;
    mask_cnt += mask;
    mexp_cnt += mexp;
    #pragma unroll
    for (int v = 0; v < VB; ++v) vocab[v] += r[v] * mexp;

    // adjacent[j] = dot(recon[:,j], recon[:,j+1]) * (target[j+1]!=PAD)
    float adj = 0.f;
    #pragma unroll
    for (int v = 0; v < VB; ++v) adj += r[v] * __shfl_down(r[v], 1, 64);
    const int tgt_next = __shfl_down(tgt, 1, 64);
    adj = (lane < 63 && tgt_next != PAD_TOK) ? adj : 0.f;

    // lane j accumulates sum_k (k+1)^2.5 * prod(adj[j..j+k]); shuffles within
    // each 8-group are independent of the p-chain -> pipeline, 1 ballot/group.
    float p = adj;
    consec_acc += p;                       // k = 0, weight 1
    #pragma unroll 1
    for (int k0 = 1; k0 < 62; k0 += 8) {
      #pragma unroll
      for (int u = 0; u < 8; ++u) {
        const int k = k0 + u;
        float sh = __shfl(adj, lane + k, 64);
        sh = (k <= 61 && lane + k <= 62) ? sh : 0.f;
        p *= sh;
        consec_acc += w_pow[k] * p;
      }
      if (__ballot(p != 0.f) == 0ull) break;  // all windows underflowed
    }
  }

  // KL + classifier terms, grid-strided over all threads
  const int gid = blockIdx.x * 256 + threadIdx.x;
  const int gstride = nblocks * 256;
  float kl = 0.f, cl = 0.f;
  for (int i = gid; i < nz; i += gstride) {
    const float m = zm[i], lv = zlv[i];
    kl += 1.f + lv - m * m - __expf(lv);
  }
  for (int i = gid; i < nc; i += gstride) cl += __logf(cs[i] + 1e-7f);

  loss_acc   = wave_red(loss_acc);
  mask_cnt   = wave_red(mask_cnt);
  consec_acc = wave_red(consec_acc);
  mexp_cnt   = wave_red(mexp_cnt);
  kl         = wave_red(kl);
  cl         = wave_red(cl);
  #pragma unroll
  for (int v = 0; v < VB; ++v) vocab[v] = wave_red(vocab[v]);

  if (lane == 0) {
    red[wid][0] = loss_acc; red[wid][1] = mask_cnt;
    red[wid][2] = consec_acc; red[wid][3] = mexp_cnt;
    red[wid][4] = kl; red[wid][5] = cl;
    #pragma unroll
    for (int v = 0; v < VB; ++v) red[wid][6 + v] = vocab[v];
  }
  __syncthreads();

  float* bank = ws + ((blockIdx.x & (REPL - 1)) << 6);
  if (threadIdx.x < NSLOT) {
    const int t = threadIdx.x;
    atomicAdd(&bank[t], red[0][t] + red[1][t] + red[2][t] + red[3][t]);
  }
  __threadfence();
  __syncthreads();
  if (threadIdx.x == 0) {
    unsigned old = atomicAdd(reinterpret_cast<unsigned*>(ws + CNT_IDX), 1u);
    last_flag = (old == (unsigned)(nblocks - 1)) ? 1 : 0;
  }
  __syncthreads();

  if (last_flag) {
    if (threadIdx.x < NSLOT) {
      float tot = 0.f;
      #pragma unroll
      for (int rp2 = 0; rp2 < REPL; ++rp2)
        tot += atomicAdd(&ws[(rp2 << 6) + threadIdx.x], 0.f);  // coherent read
      fin[threadIdx.x] = tot;
    }
    __syncthreads();
    if (threadIdx.x == 0) {
      const float freqs[VB] = {0.0817f,0.0149f,0.0278f,0.0425f,0.127f,0.0223f,
        0.0202f,0.0609f,0.0697f,0.0015f,0.0077f,0.0403f,0.0241f,0.0675f,0.0751f,
        0.0193f,0.001f,0.0599f,0.0633f,0.0906f,0.0276f,0.0098f,0.0236f,0.0015f,
        0.0197f,0.0007f,0.f,0.f};
      const float rec_loss = fin[0] / fin[1];
      const float kl_loss  = -0.5f * fin[4] / (float)nz;
      const float cls_loss = -fin[5] / (float)nc;
      const float inv_mexp = 1.f / fin[3];
      float fp = 0.f;
      #pragma unroll
      for (int v = 0; v < VB; ++v)
        fp += fmaxf(0.f, fin[6 + v] * inv_mexp - freqs[v]);
      out[0] = rec_loss + 0.1f * kl_loss + 2.f * cls_loss
             + 0.2f * fin[2] + 0.5f * fp;
    }
  }
}

extern "C" void kernel_launch(void* const* d_in, const int* in_sizes, int n_in,
                              void* d_out, int out_size, void* d_ws, size_t ws_size,
                              hipStream_t stream) {
  const float* x   = (const float*)d_in[0];
  const float* rec = (const float*)d_in[1];
  const float* zm  = (const float*)d_in[2];
  const float* zlv = (const float*)d_in[3];
  const float* cs  = (const float*)d_in[4];
  float* out = (float*)d_out;
  float* ws  = (float*)d_ws;

  const int nrows = in_sizes[0] / (LL * VB);     // B
  const int nz    = in_sizes[2];                 // B * LATENT
  const int nc    = in_sizes[4];                 // B

  int nblocks = (nrows + 3) / 4;                 // 1 row per wave
  if (nblocks < 1) nblocks = 1;

  hipMemsetAsync(d_ws, 0, (CNT_IDX + 4) * sizeof(float), stream);
  vae_fused<<<nblocks, 256, 0, stream>>>(x, rec, zm, zlv, cs, ws, out,
                                         nrows, nz, nc, nblocks);
}